// Round 2
// baseline (1422.344 us; speedup 1.0000x reference)
//
#include <hip/hip_runtime.h>
#include <hip/hip_bf16.h>
#include <stdint.h>

typedef float v4f __attribute__((ext_vector_type(4)));
typedef short v8s __attribute__((ext_vector_type(8)));
typedef uint16_t u16;

__device__ __forceinline__ void gload_lds16(const u16* g, u16* l) {
  __builtin_amdgcn_global_load_lds(
      (const __attribute__((address_space(1))) void*)g,
      (__attribute__((address_space(3))) void*)l, 16, 0, 0);
}

// ---------------------------------------------------------------------------
// Fused Hadamard-rotate (FWHT) + MXFP4 quant-dequant -> bf16 (unchanged, works)
// ---------------------------------------------------------------------------
__global__ __launch_bounds__(256) void quant_rot_kernel(
    const float* __restrict__ in, u16* __restrict__ out, int ngroups) {
  int g = blockIdx.x * 256 + threadIdx.x;
  if (g >= ngroups) return;

  float v[32];
  const v4f* p = (const v4f*)(in + (size_t)g * 32);
#pragma unroll
  for (int c = 0; c < 8; ++c) {
    v4f t = p[c];
    v[c * 4 + 0] = t[0]; v[c * 4 + 1] = t[1];
    v[c * 4 + 2] = t[2]; v[c * 4 + 3] = t[3];
  }
#pragma unroll
  for (int s = 0; s < 5; ++s) {
    const int h = 1 << s;
#pragma unroll
    for (int k = 0; k < 16; ++k) {
      const int i = ((k >> s) << (s + 1)) | (k & (h - 1));
      float a = v[i], b = v[i + h];
      v[i] = a + b; v[i + h] = a - b;
    }
  }
  const float RS = 0.17677669529663687f;  // 32^-0.5
  float amax = 0.0f;
#pragma unroll
  for (int i = 0; i < 32; ++i) {
    v[i] *= RS;
    amax = fmaxf(amax, fabsf(v[i]));
  }
  float scale, rscale;
  if (amax > 0.0f) {
    float am = fmaxf(amax, 1e-30f);
    int E = (int)((__float_as_uint(am) >> 23) & 255u) - 127;
    scale  = __uint_as_float((uint32_t)(E - 2 + 127) << 23);
    rscale = __uint_as_float((uint32_t)(2 - E + 127) << 23);
  } else { scale = 1.0f; rscale = 1.0f; }

  u16 o[32];
#pragma unroll
  for (int i = 0; i < 32; ++i) {
    float x = v[i];
    float a = fminf(fabsf(x) * rscale, 6.0f);
    float rstep = a >= 4.0f ? 0.5f : (a >= 2.0f ? 1.0f : 2.0f);
    float step  = a >= 4.0f ? 2.0f : (a >= 2.0f ? 1.0f : 0.5f);
    float q = rintf(a * rstep) * step;           // RNE
    float d = copysignf(q * scale, x);           // exact in bf16
    o[i] = (u16)(__float_as_uint(d) >> 16);
  }
  uint4* dst = (uint4*)(out + (size_t)g * 32);
  const uint4* src = (const uint4*)o;
#pragma unroll
  for (int c = 0; c < 4; ++c) dst[c] = src[c];
}

// ---------------------------------------------------------------------------
// bf16 GEMM, B^T: C[m][n] = sum_k A[m][k]*B[n][k] + bias[n]
// 256x256 tile, BK=32, 8 waves (2Mx4N), 3-deep LDS ring, counted vmcnt,
// st-style XOR swizzle (both sides), setprio around MFMA, XCD block swizzle.
// ---------------------------------------------------------------------------
__global__ __launch_bounds__(512, 2) void gemm_bf16_bt_256(
    const u16* __restrict__ A, const u16* __restrict__ B,
    const float* __restrict__ bias, float* __restrict__ C) {
  const int N = 16384, K = 4096, NT = 128;
  // 96 KB: ring buf b at lds[b*16384]; A = first 8192 u16, B = next 8192 u16
  __shared__ u16 lds[3 * 16384];

  const int tid  = threadIdx.x;
  const int lane = tid & 63;
  const int wv   = tid >> 6;     // 0..7
  const int wm   = wv >> 2;      // 0..1  (M half)
  const int wn   = wv & 3;       // 0..3  (N quarter)

  // XCD swizzle: 2048 blocks, 8 XCDs; XCD x gets contiguous swz chunk.
  // m-fastest: 32 concurrent CUs of one XCD share one B panel (L2-hit).
  const int bid = blockIdx.x;
  const int swz = (bid & 7) * 256 + (bid >> 3);
  const int mTile = (swz & 31) * 256;
  const int nTile = (swz >> 5) * 256;

  // ---- staging: 1024 16B-chunks/tile; thread stages chunks tid, tid+512.
  // LDS dest is LINEAR (gload_lds requirement); the SOURCE is the inverse
  // of swz(row,g): row_s = row ^ bit2(row), slot_s = g ^ (row&3).
  int srcA[2], srcB[2], dst[2];
#pragma unroll
  for (int j = 0; j < 2; ++j) {
    int p = j * 512 + tid;             // swizzled 16B-chunk index
    int row_s = p >> 2, s = p & 3;
    int row = row_s ^ ((row_s >> 2) & 1);
    int g = s ^ (row & 3);
    dst[j]  = p * 8;                   // u16 units
    srcA[j] = (mTile + row) * K + g * 8;
    srcB[j] = (nTile + row) * K + g * 8;
  }

  // ---- read side: lane (r,gg) reads chunk (R0+r, gg) at swizzled address
  const int r = lane & 15, gg = lane >> 4;
  const int rsw = (r ^ ((r >> 2) & 1)) * 32 + ((gg ^ (r & 3)) * 8);  // u16

  v4f acc[8][4] = {};

  auto STAGE = [&](int t, int b) {
    u16* base = &lds[b * 16384];
    const int k0 = t * 32;
    gload_lds16(A + (size_t)(srcA[0] + k0), base + dst[0]);
    gload_lds16(A + (size_t)(srcA[1] + k0), base + dst[1]);
    gload_lds16(B + (size_t)(srcB[0] + k0), base + 8192 + dst[0]);
    gload_lds16(B + (size_t)(srcB[1] + k0), base + 8192 + dst[1]);
  };

  // prologue: tiles 0,1 in flight; wait tile 0 only
  STAGE(0, 0);
  STAGE(1, 1);
  asm volatile("s_waitcnt vmcnt(4)" ::: "memory");
  __builtin_amdgcn_s_barrier();

  int cs = 0;  // buffer holding tile t
  for (int t = 0; t < NT; ++t) {
    int ps = cs == 0 ? 2 : cs - 1;     // (t+2)%3
    if (t + 2 < NT) STAGE(t + 2, ps);

    const u16* bA = &lds[cs * 16384];
    const u16* bB = bA + 8192;
    v8s af[8], bf[4];
#pragma unroll
    for (int i = 0; i < 8; ++i)
      af[i] = *(const v8s*)(bA + wm * 4096 + i * 512 + rsw);
#pragma unroll
    for (int j = 0; j < 4; ++j)
      bf[j] = *(const v8s*)(bB + wn * 2048 + j * 512 + rsw);

    __builtin_amdgcn_s_setprio(1);
#pragma unroll
    for (int i = 0; i < 8; ++i)
#pragma unroll
      for (int j = 0; j < 4; ++j)
        acc[i][j] = __builtin_amdgcn_mfma_f32_16x16x32_bf16(af[i], bf[j],
                                                            acc[i][j], 0, 0, 0);
    __builtin_amdgcn_s_setprio(0);

    if (t + 1 < NT) {
      // tile t+1 must be fully resident; tile t+2 (4 loads) stays in flight
      if (t + 2 < NT) asm volatile("s_waitcnt vmcnt(4)" ::: "memory");
      else            asm volatile("s_waitcnt vmcnt(0)" ::: "memory");
      __builtin_amdgcn_s_barrier();
    }
    cs = cs == 2 ? 0 : cs + 1;
  }

  // epilogue: C/D layout col=lane&15, row=(lane>>4)*4+reg (m89-verified)
#pragma unroll
  for (int j = 0; j < 4; ++j) {
    const int col = nTile + wn * 64 + j * 16 + r;
    const float bv = bias[col];
#pragma unroll
    for (int i = 0; i < 8; ++i) {
      const int row0 = mTile + wm * 128 + i * 16 + gg * 4;
#pragma unroll
      for (int q = 0; q < 4; ++q)
        C[(size_t)(row0 + q) * N + col] = acc[i][j][q] + bv;
    }
  }
}

// ---------------------------------------------------------------------------
extern "C" void kernel_launch(void* const* d_in, const int* in_sizes, int n_in,
                              void* d_out, int out_size, void* d_ws, size_t ws_size,
                              hipStream_t stream) {
  const float* x    = (const float*)d_in[0];   // 8192 x 4096
  const float* w    = (const float*)d_in[1];   // 16384 x 4096
  const float* bias = (const float*)d_in[2];   // 16384
  float* out = (float*)d_out;                  // 8192 x 16384 fp32

  const int M = 8192, N = 16384, K = 4096;
  u16* x_dq = (u16*)d_ws;                                  // 64 MB
  u16* w_dq = (u16*)((char*)d_ws + (size_t)M * K * 2);     // 128 MB

  const int xg = M * K / 32;
  const int wg = N * K / 32;
  quant_rot_kernel<<<xg / 256, 256, 0, stream>>>(x, x_dq, xg);
  quant_rot_kernel<<<wg / 256, 256, 0, stream>>>(w, w_dq, wg);

  gemm_bf16_bt_256<<<(M / 256) * (N / 256), dim3(512), 0, stream>>>(
      x_dq, w_dq, bias, out);
}

// Round 3
// 1041.734 us; speedup vs baseline: 1.3654x; 1.3654x over previous
//
#include <hip/hip_runtime.h>
#include <hip/hip_bf16.h>
#include <stdint.h>

typedef float v4f __attribute__((ext_vector_type(4)));
typedef short v8s __attribute__((ext_vector_type(8)));
typedef uint16_t u16;

__device__ __forceinline__ void gload_lds16(const u16* g, u16* l) {
  __builtin_amdgcn_global_load_lds(
      (const __attribute__((address_space(1))) void*)g,
      (__attribute__((address_space(3))) void*)l, 16, 0, 0);
}

// ---------------------------------------------------------------------------
// Fused Hadamard-rotate (FWHT) + MXFP4 quant-dequant -> bf16 (proven, keep)
// ---------------------------------------------------------------------------
__global__ __launch_bounds__(256) void quant_rot_kernel(
    const float* __restrict__ in, u16* __restrict__ out, int ngroups) {
  int g = blockIdx.x * 256 + threadIdx.x;
  if (g >= ngroups) return;

  float v[32];
  const v4f* p = (const v4f*)(in + (size_t)g * 32);
#pragma unroll
  for (int c = 0; c < 8; ++c) {
    v4f t = p[c];
    v[c * 4 + 0] = t[0]; v[c * 4 + 1] = t[1];
    v[c * 4 + 2] = t[2]; v[c * 4 + 3] = t[3];
  }
#pragma unroll
  for (int s = 0; s < 5; ++s) {
    const int h = 1 << s;
#pragma unroll
    for (int k = 0; k < 16; ++k) {
      const int i = ((k >> s) << (s + 1)) | (k & (h - 1));
      float a = v[i], b = v[i + h];
      v[i] = a + b; v[i + h] = a - b;
    }
  }
  const float RS = 0.17677669529663687f;  // 32^-0.5
  float amax = 0.0f;
#pragma unroll
  for (int i = 0; i < 32; ++i) {
    v[i] *= RS;
    amax = fmaxf(amax, fabsf(v[i]));
  }
  float scale, rscale;
  if (amax > 0.0f) {
    float am = fmaxf(amax, 1e-30f);
    int E = (int)((__float_as_uint(am) >> 23) & 255u) - 127;
    scale  = __uint_as_float((uint32_t)(E - 2 + 127) << 23);
    rscale = __uint_as_float((uint32_t)(2 - E + 127) << 23);
  } else { scale = 1.0f; rscale = 1.0f; }

  u16 o[32];
#pragma unroll
  for (int i = 0; i < 32; ++i) {
    float x = v[i];
    float a = fminf(fabsf(x) * rscale, 6.0f);
    float rstep = a >= 4.0f ? 0.5f : (a >= 2.0f ? 1.0f : 2.0f);
    float step  = a >= 4.0f ? 2.0f : (a >= 2.0f ? 1.0f : 0.5f);
    float q = rintf(a * rstep) * step;           // RNE
    float d = copysignf(q * scale, x);           // exact in bf16
    o[i] = (u16)(__float_as_uint(d) >> 16);
  }
  uint4* dst = (uint4*)(out + (size_t)g * 32);
  const uint4* src = (const uint4*)o;
#pragma unroll
  for (int c = 0; c < 4; ++c) dst[c] = src[c];
}

// ---------------------------------------------------------------------------
// bf16 GEMM, B^T: C[m][n] = sum_k A[m][k]*B[n][k] + bias[n]
// 256x256 / BK=64 / 8 waves / 128KB LDS / 8-phase counted-vmcnt schedule
// (m201 template). LDS swizzle: byte ^= (row&7)<<4, both-sides (rule #21).
// ---------------------------------------------------------------------------
#define MFMA16 __builtin_amdgcn_mfma_f32_16x16x32_bf16
#define BARRIER { asm volatile("" ::: "memory"); __builtin_amdgcn_s_barrier(); asm volatile("" ::: "memory"); }
#define LGKM0  asm volatile("s_waitcnt lgkmcnt(0)" ::: "memory")
#define VMW(n) asm volatile("s_waitcnt vmcnt(" #n ")" ::: "memory")

__global__ __launch_bounds__(512, 2) void gemm_8phase(
    const u16* __restrict__ A, const u16* __restrict__ B,
    const float* __restrict__ bias, float* __restrict__ C) {
  const int N = 16384, K = 4096;
  const int BUF1 = 32768;  // u16 offset of second K-tile buffer
  // 128 KB: [buf:2][ A:2 halves x 128x64 | B:2 halves x 128x64 ] bf16
  __shared__ u16 lds[65536];

  const int tid  = threadIdx.x;
  const int lane = tid & 63;
  const int wv   = tid >> 6;
  const int wm   = wv >> 2;       // 0..1 (A half / 128 M-rows)
  const int wn   = wv & 3;        // 0..3 (64 N-rows)

  // XCD-aware 8m x 4n super-tile clusters (grid 2048 = 32m x 64n, 2048%8==0)
  const int xcd = blockIdx.x & 7;
  const int idx = blockIdx.x >> 3;          // 0..255 within XCD
  const int st  = idx >> 5;                 // 8 super-tiles of 32 blocks
  const int mT  = ((st & 3) * 8 + (idx & 7)) * 256;
  const int nT  = (xcd * 8 + (st >> 2) * 4 + ((idx >> 3) & 3)) * 256;

  // ---- staging precompute: linear LDS dest, inverse-swizzled global source.
  // Within a 16KB half (128 rows x 128B): swz(byte) = byte ^ ((row&7)<<4).
  int grow[2], gcol[2], dstu[2];
#pragma unroll
  for (int q = 0; q < 2; ++q) {
    int lb = q * 8192 + tid * 16;                 // linear byte in half
    int go = lb ^ (((lb >> 7) & 7) << 4);         // involution (row unchanged)
    grow[q] = go >> 7;                            // 0..127
    gcol[q] = (go & 127) >> 1;                    // u16 col 0..63
    dstu[q] = lb >> 1;                            // u16 offset in half
  }
  const u16* sA0 = A + (size_t)(mT + grow[0]) * K + gcol[0];
  const u16* sA1 = A + (size_t)(mT + grow[1]) * K + gcol[1];
  const u16* sB0 = B + (size_t)(nT + grow[0]) * K + gcol[0];
  const u16* sB1 = B + (size_t)(nT + grow[1]) * K + gcol[1];

#define STG_A(t, h, bb) { \
    gload_lds16(sA0 + (size_t)(h) * (128 * 4096) + (t) * 64, &lds[(bb) + (h) * 8192 + dstu[0]]); \
    gload_lds16(sA1 + (size_t)(h) * (128 * 4096) + (t) * 64, &lds[(bb) + (h) * 8192 + dstu[1]]); }
#define STG_B(t, h, bb) { \
    gload_lds16(sB0 + (size_t)(h) * (128 * 4096) + (t) * 64, &lds[(bb) + 16384 + (h) * 8192 + dstu[0]]); \
    gload_lds16(sB1 + (size_t)(h) * (128 * 4096) + (t) * 64, &lds[(bb) + 16384 + (h) * 8192 + dstu[1]]); }

  // ---- fragment read addressing (swizzled): u16 col = c ^ ((row&7)*8)
  const int r  = lane & 15, gg = lane >> 4;
  const int sw = (r & 7) * 8;
  const int c0 = (gg * 8) ^ sw;            // kk=0
  const int c1 = (32 + gg * 8) ^ sw;       // kk=1
  const int aoff = wm * 8192 + r * 64;     // wave's A region + frag row
  const int boff = 16384 + (wn >> 1) * 8192 + (wn & 1) * 4096 + r * 64;

  v4f acc[8][4] = {};
  v8s Af[4][2], Bq0[2][2], Bq1[2][2];

#define LD_A(bb, mh) { \
  _Pragma("unroll") for (int f = 0; f < 4; ++f) { \
    Af[f][0] = *(const v8s*)&lds[(bb) + aoff + ((mh) * 4 + f) * 1024 + c0]; \
    Af[f][1] = *(const v8s*)&lds[(bb) + aoff + ((mh) * 4 + f) * 1024 + c1]; } }
#define LD_B(bb, nh, Bq) { \
  _Pragma("unroll") for (int j = 0; j < 2; ++j) { \
    Bq[j][0] = *(const v8s*)&lds[(bb) + boff + ((nh) * 2 + j) * 1024 + c0]; \
    Bq[j][1] = *(const v8s*)&lds[(bb) + boff + ((nh) * 2 + j) * 1024 + c1]; } }
#define MM_Q(mh, nh, Bq) { \
  __builtin_amdgcn_s_setprio(1); \
  _Pragma("unroll") for (int f = 0; f < 4; ++f) \
  _Pragma("unroll") for (int j = 0; j < 2; ++j) { \
    acc[(mh)*4+f][(nh)*2+j] = MFMA16(Af[f][0], Bq[j][0], acc[(mh)*4+f][(nh)*2+j], 0, 0, 0); \
    acc[(mh)*4+f][(nh)*2+j] = MFMA16(Af[f][1], Bq[j][1], acc[(mh)*4+f][(nh)*2+j], 0, 0, 0); } \
  __builtin_amdgcn_s_setprio(0); }

  // ---- prologue: tile0 (4 halves) + first half of tile1; vmcnt(2) keeps
  // the last issue in flight.
  STG_A(0, 0, 0); STG_A(0, 1, 0); STG_B(0, 0, 0); STG_B(0, 1, 0);
  STG_A(1, 0, BUF1);
  VMW(2);
  BARRIER;

  // ---- main loop: 32 iters x 2 K-tiles (K=4096, BK=64)
  for (int i = 0; i < 32; ++i) {
    const int T = 2 * i;
    const bool nl = (i != 31);
    // ph1: reads A[mh0],B[nh0] of tile T (buf0); completes tile T+1's A1
    LD_A(0, 0); LD_B(0, 0, Bq0);
    STG_A(T + 1, 1, BUF1);
    BARRIER; LGKM0; MM_Q(0, 0, Bq0); BARRIER;
    // ph2
    LD_B(0, 1, Bq1);
    STG_B(T + 1, 0, BUF1);
    BARRIER; LGKM0; MM_Q(0, 1, Bq1); BARRIER;
    // ph3
    LD_A(0, 1);
    STG_B(T + 1, 1, BUF1);
    BARRIER; LGKM0; MM_Q(1, 1, Bq1); BARRIER;
    // ph4: buf0's tile T fully read after ph3 -> start overwriting with T+2
    if (nl) STG_A(T + 2, 0, 0);
    BARRIER; MM_Q(1, 0, Bq0);
    if (nl) { VMW(2); } else { VMW(0); }   // tile T+1 resident; ph4 issue in flight
    BARRIER;
    // ph5: tile T+1 (buf1)
    LD_A(BUF1, 0); LD_B(BUF1, 0, Bq0);
    if (nl) STG_A(T + 2, 1, 0);
    BARRIER; LGKM0; MM_Q(0, 0, Bq0); BARRIER;
    // ph6
    LD_B(BUF1, 1, Bq1);
    if (nl) STG_B(T + 2, 0, 0);
    BARRIER; LGKM0; MM_Q(0, 1, Bq1); BARRIER;
    // ph7
    LD_A(BUF1, 1);
    if (nl) STG_B(T + 2, 1, 0);
    BARRIER; LGKM0; MM_Q(1, 1, Bq1); BARRIER;
    // ph8: buf1's tile T+1 fully read -> first half of T+3
    if (nl) STG_A(T + 3, 0, BUF1);
    BARRIER; MM_Q(1, 0, Bq0);
    if (nl) VMW(2);                        // tile T+2 resident; ph8 issue in flight
    BARRIER;
  }

  // ---- epilogue: C/D layout col=lane&15, row=(lane>>4)*4+reg (m89-verified)
#pragma unroll
  for (int j = 0; j < 4; ++j) {
    const int col = nT + wn * 64 + j * 16 + r;
    const float bv = bias[col];
#pragma unroll
    for (int f = 0; f < 8; ++f) {
      const int row0 = mT + wm * 128 + f * 16 + gg * 4;
#pragma unroll
      for (int q = 0; q < 4; ++q)
        C[(size_t)(row0 + q) * N + col] = acc[f][j][q] + bv;
    }
  }
}

// ---------------------------------------------------------------------------
extern "C" void kernel_launch(void* const* d_in, const int* in_sizes, int n_in,
                              void* d_out, int out_size, void* d_ws, size_t ws_size,
                              hipStream_t stream) {
  const float* x    = (const float*)d_in[0];   // 8192 x 4096
  const float* w    = (const float*)d_in[1];   // 16384 x 4096
  const float* bias = (const float*)d_in[2];   // 16384
  float* out = (float*)d_out;                  // 8192 x 16384 fp32

  const int M = 8192, N = 16384, K = 4096;
  u16* x_dq = (u16*)d_ws;                                  // 64 MB
  u16* w_dq = (u16*)((char*)d_ws + (size_t)M * K * 2);     // 128 MB

  const int xg = M * K / 32;
  const int wg = N * K / 32;
  quant_rot_kernel<<<xg / 256, 256, 0, stream>>>(x, x_dq, xg);
  quant_rot_kernel<<<wg / 256, 256, 0, stream>>>(w, w_dq, wg);

  gemm_8phase<<<(M / 256) * (N / 256), dim3(512), 0, stream>>>(
      x_dq, w_dq, bias, out);
}

// Round 4
// 754.673 us; speedup vs baseline: 1.8847x; 1.3804x over previous
//
#include <hip/hip_runtime.h>
#include <stdint.h>

typedef float v4f  __attribute__((ext_vector_type(4)));
typedef float v16f __attribute__((ext_vector_type(16)));
typedef int   v4i  __attribute__((ext_vector_type(4)));
typedef int   v8i  __attribute__((ext_vector_type(8)));

__device__ __forceinline__ void gload_lds16(const void* g, void* l) {
  __builtin_amdgcn_global_load_lds(
      (const __attribute__((address_space(1))) void*)g,
      (__attribute__((address_space(3))) void*)l, 16, 0, 0);
}

// ---------------------------------------------------------------------------
// Fused FWHT + MXFP4 quantize -> packed e2m1 nibbles + E8M0 scale bytes.
// One 32-group per thread. Packed: group g -> 16B at g*16 (elem j: dword j>>3,
// bits 4*(j&7), low nibble first). Scales: byte for (row, kb) stored at
// dword[(kt*2+hi)*R + row], byte lane ks, where kt=kb>>3, hi=kb&1, ks=(kb>>1)&3.
// ---------------------------------------------------------------------------
__global__ __launch_bounds__(256) void quant_fp4_kernel(
    const float* __restrict__ in, uint32_t* __restrict__ packed,
    uint8_t* __restrict__ scales, int R) {
  int g = blockIdx.x * 256 + threadIdx.x;   // grid sized exactly

  float v[32];
  const v4f* p = (const v4f*)(in + (size_t)g * 32);
#pragma unroll
  for (int c = 0; c < 8; ++c) {
    v4f t = p[c];
    v[c * 4 + 0] = t[0]; v[c * 4 + 1] = t[1];
    v[c * 4 + 2] = t[2]; v[c * 4 + 3] = t[3];
  }
#pragma unroll
  for (int s = 0; s < 5; ++s) {
    const int h = 1 << s;
#pragma unroll
    for (int k = 0; k < 16; ++k) {
      const int i = ((k >> s) << (s + 1)) | (k & (h - 1));
      float a = v[i], b = v[i + h];
      v[i] = a + b; v[i + h] = a - b;
    }
  }
  const float RS = 0.17677669529663687f;  // 32^-0.5
  float amax = 0.0f;
#pragma unroll
  for (int i = 0; i < 32; ++i) {
    v[i] *= RS;
    amax = fmaxf(amax, fabsf(v[i]));
  }
  int E;          // scale = 2^(E-2); E8M0 byte = E - 2 + 127
  float rscale;   // 2^(2-E), exact
  if (amax > 0.0f) {
    float am = fmaxf(amax, 1e-30f);
    E = (int)((__float_as_uint(am) >> 23) & 255u) - 127;
    rscale = __uint_as_float((uint32_t)(2 - E + 127) << 23);
  } else { E = 2; rscale = 1.0f; }

  uint32_t dw[4] = {0u, 0u, 0u, 0u};
#pragma unroll
  for (int i = 0; i < 32; ++i) {
    float x = v[i];
    float a = fminf(fabsf(x) * rscale, 6.0f);
    float rstep = a >= 4.0f ? 0.5f : (a >= 2.0f ? 1.0f : 2.0f);
    float step  = a >= 4.0f ? 2.0f : (a >= 2.0f ? 1.0f : 0.5f);
    float q = rintf(a * rstep) * step;          // RNE onto {0,.5,1,1.5,2,3,4,6}
    uint32_t uq = __float_as_uint(q);
    int Eq = (int)(uq >> 23) - 127;
    uint32_t code = (q == 0.0f) ? 0u
                  : (Eq < 0 ? 1u
                            : (((uint32_t)(Eq + 1) << 1) | ((uq >> 22) & 1u)));
    code |= (__float_as_uint(x) >> 31) << 3;    // sign
    dw[i >> 3] |= code << (4 * (i & 7));
  }
  uint4 o; o.x = dw[0]; o.y = dw[1]; o.z = dw[2]; o.w = dw[3];
  *(uint4*)(packed + (size_t)g * 4) = o;

  int row = g >> 7, kb = g & 127;               // K/32 = 128 groups per row
  int kt = kb >> 3, hi = kb & 1, ks = (kb >> 1) & 3;
  scales[(size_t)((kt * 2 + hi) * R + row) * 4 + ks] = (uint8_t)(E - 2 + 127);
}

// ---------------------------------------------------------------------------
// MXFP4 GEMM, B^T: C[m][n] = sum_k sA*sB*(a*b) + bias[n]
// 128x128 tile, BK=256, 4 waves (2x2), each wave 64x64 = 2x2 MFMA 32x32x64.
// k-major LDS [kc 0..7][row 0..127] 16B chunks: conflict-free ds_read_b128.
// ---------------------------------------------------------------------------
__device__ __forceinline__ v8i frag4(const uint8_t* p) {
  v4i lo = *(const v4i*)p;
  v8i r;
  r[0] = lo[0]; r[1] = lo[1]; r[2] = lo[2]; r[3] = lo[3];
  r[4] = 0; r[5] = 0; r[6] = 0; r[7] = 0;   // fp4 uses v[0:3] only
  return r;
}

#define MFMA4(a, b, c, sa, sb) \
  __builtin_amdgcn_mfma_scale_f32_32x32x64_f8f6f4((a), (b), (c), 4, 4, 0, (sa), 0, (sb))

__global__ __launch_bounds__(256, 2) void gemm_fp4(
    const uint8_t* __restrict__ Apk, const uint8_t* __restrict__ Bpk,
    const uint32_t* __restrict__ Asc, const uint32_t* __restrict__ Bsc,
    const float* __restrict__ bias, float* __restrict__ C) {
  const int N = 16384;
  __shared__ uint8_t ldsA[16384];   // 8 kc x 128 rows x 16B
  __shared__ uint8_t ldsB[16384];

  const int tid = threadIdx.x, lane = tid & 63, wv = tid >> 6;
  const int wm = wv >> 1, wn = wv & 1;
  const int hi = lane >> 5, r32 = lane & 31;

  // XCD swizzle: 8192 blocks, m-fastest within each XCD's contiguous chunk
  const int bid = blockIdx.x;
  const int swz = (bid & 7) * 1024 + (bid >> 3);
  const int mT = (swz & 63) * 128;
  const int nT = (swz >> 6) * 128;

  // staging: 1024 chunks per operand; thread stages 4 (p = q*256+tid)
  size_t srcA[4], srcB[4];
  int dstL[4];
#pragma unroll
  for (int q = 0; q < 4; ++q) {
    int pc = q * 256 + tid;
    int kc = pc >> 7, row = pc & 127;
    dstL[q] = pc * 16;
    srcA[q] = (size_t)(mT + row) * 2048 + kc * 16;
    srcB[q] = (size_t)(nT + row) * 2048 + kc * 16;
  }

  // scale pointers: dword (kt*2+hi)*R + row ; bytes = ks 0..3
  const uint32_t* aScP = Asc + hi * 8192  + mT + wm * 64 + r32;
  const uint32_t* bScP = Bsc + hi * 16384 + nT + wn * 64 + r32;

  // fragment read bases (k-major, conflict-free)
  const uint8_t* ardB = ldsA + hi * 2048 + (wm * 64 + r32) * 16;
  const uint8_t* brdB = ldsB + hi * 2048 + (wn * 64 + r32) * 16;

  v16f acc[2][2] = {};

  for (int kt = 0; kt < 16; ++kt) {
#pragma unroll
    for (int q = 0; q < 4; ++q)
      gload_lds16(Apk + srcA[q] + kt * 128, ldsA + dstL[q]);
#pragma unroll
    for (int q = 0; q < 4; ++q)
      gload_lds16(Bpk + srcB[q] + kt * 128, ldsB + dstL[q]);
    uint32_t sa0 = aScP[kt * 16384], sa1 = aScP[kt * 16384 + 32];
    uint32_t sb0 = bScP[kt * 32768], sb1 = bScP[kt * 32768 + 32];
    __syncthreads();   // drains vmcnt: tile + scales resident

#pragma unroll
    for (int ks = 0; ks < 4; ++ks) {
      v8i a0 = frag4(ardB + ks * 4096);
      v8i a1 = frag4(ardB + ks * 4096 + 512);
      v8i b0 = frag4(brdB + ks * 4096);
      v8i b1 = frag4(brdB + ks * 4096 + 512);
      int xa0 = (int)((sa0 >> (8 * ks)) & 255u);
      int xa1 = (int)((sa1 >> (8 * ks)) & 255u);
      int xb0 = (int)((sb0 >> (8 * ks)) & 255u);
      int xb1 = (int)((sb1 >> (8 * ks)) & 255u);
      acc[0][0] = MFMA4(a0, b0, acc[0][0], xa0, xb0);
      acc[0][1] = MFMA4(a0, b1, acc[0][1], xa0, xb1);
      acc[1][0] = MFMA4(a1, b0, acc[1][0], xa1, xb0);
      acc[1][1] = MFMA4(a1, b1, acc[1][1], xa1, xb1);
    }
    __syncthreads();
  }

  // epilogue: 32x32 C/D layout col=lane&31, row=(reg&3)+8*(reg>>2)+4*(lane>>5)
  // (m74/m101; shape-determined for the scaled op per m121-m128)
#pragma unroll
  for (int nb = 0; nb < 2; ++nb) {
    const int col = nT + wn * 64 + nb * 32 + r32;
    const float bv = bias[col];
#pragma unroll
    for (int mb = 0; mb < 2; ++mb) {
      const int rbase = mT + wm * 64 + mb * 32 + 4 * hi;
#pragma unroll
      for (int r = 0; r < 16; ++r) {
        const int rowl = (r & 3) + 8 * (r >> 2);
        C[(size_t)(rbase + rowl) * N + col] = acc[mb][nb][r] + bv;
      }
    }
  }
}

// ---------------------------------------------------------------------------
extern "C" void kernel_launch(void* const* d_in, const int* in_sizes, int n_in,
                              void* d_out, int out_size, void* d_ws, size_t ws_size,
                              hipStream_t stream) {
  const float* x    = (const float*)d_in[0];   // 8192 x 4096
  const float* w    = (const float*)d_in[1];   // 16384 x 4096
  const float* bias = (const float*)d_in[2];   // 16384
  float* out = (float*)d_out;                  // 8192 x 16384 fp32

  uint8_t* x_pk = (uint8_t*)d_ws;                        // 16 MB
  uint8_t* w_pk = x_pk + (size_t)16 * 1024 * 1024;       // 32 MB
  uint8_t* x_sc = w_pk + (size_t)32 * 1024 * 1024;       // 1 MB
  uint8_t* w_sc = x_sc + (size_t)1  * 1024 * 1024;       // 2 MB

  quant_fp4_kernel<<<4096, 256, 0, stream>>>(x, (uint32_t*)x_pk, x_sc, 8192);
  quant_fp4_kernel<<<8192, 256, 0, stream>>>(w, (uint32_t*)w_pk, w_sc, 16384);

  gemm_fp4<<<8192, 256, 0, stream>>>(x_pk, w_pk, (const uint32_t*)x_sc,
                                     (const uint32_t*)w_sc, bias, out);
}

// Round 5
// 484.389 us; speedup vs baseline: 2.9364x; 1.5580x over previous
//
#include <hip/hip_runtime.h>
#include <stdint.h>

typedef float v4f  __attribute__((ext_vector_type(4)));
typedef float v16f __attribute__((ext_vector_type(16)));
typedef int   v4i  __attribute__((ext_vector_type(4)));
typedef int   v8i  __attribute__((ext_vector_type(8)));

__device__ __forceinline__ void gload_lds16(const void* g, void* l) {
  __builtin_amdgcn_global_load_lds(
      (const __attribute__((address_space(1))) void*)g,
      (__attribute__((address_space(3))) void*)l, 16, 0, 0);
}
__device__ __forceinline__ void gload_lds4(const void* g, void* l) {
  __builtin_amdgcn_global_load_lds(
      (const __attribute__((address_space(1))) void*)g,
      (__attribute__((address_space(3))) void*)l, 4, 0, 0);
}

// ---------------------------------------------------------------------------
// Fused FWHT + MXFP4 quantize. Thread -> (kb, row): kb = g>>rshift, row =
// g & (R-1). Packed GLOBAL layout is k-major: group (kb,row) -> 16B at
// (kb*R + row)*16 (contiguous across threads => coalesced writes; reads are
// one full 128B line per thread). Scales: dword (kt*2+hi)*R + row, byte ks
// (kt=kb>>3, hi=kb&1, ks=(kb>>1)&3).
// ---------------------------------------------------------------------------
__global__ __launch_bounds__(256) void quant_fp4_kernel(
    const float* __restrict__ in, uint32_t* __restrict__ packed,
    uint8_t* __restrict__ scales, int R, int rshift) {
  int g = blockIdx.x * 256 + threadIdx.x;
  int kb = g >> rshift, row = g & (R - 1);

  float v[32];
  const v4f* p = (const v4f*)(in + (size_t)row * 4096 + kb * 32);
#pragma unroll
  for (int c = 0; c < 8; ++c) {
    v4f t = p[c];
    v[c * 4 + 0] = t[0]; v[c * 4 + 1] = t[1];
    v[c * 4 + 2] = t[2]; v[c * 4 + 3] = t[3];
  }
#pragma unroll
  for (int s = 0; s < 5; ++s) {
    const int h = 1 << s;
#pragma unroll
    for (int k = 0; k < 16; ++k) {
      const int i = ((k >> s) << (s + 1)) | (k & (h - 1));
      float a = v[i], b = v[i + h];
      v[i] = a + b; v[i + h] = a - b;
    }
  }
  const float RS = 0.17677669529663687f;  // 32^-0.5
  float amax = 0.0f;
#pragma unroll
  for (int i = 0; i < 32; ++i) {
    v[i] *= RS;
    amax = fmaxf(amax, fabsf(v[i]));
  }
  int E;
  float rscale;
  if (amax > 0.0f) {
    float am = fmaxf(amax, 1e-30f);
    E = (int)((__float_as_uint(am) >> 23) & 255u) - 127;
    rscale = __uint_as_float((uint32_t)(2 - E + 127) << 23);
  } else { E = 2; rscale = 1.0f; }

  uint32_t dw[4] = {0u, 0u, 0u, 0u};
#pragma unroll
  for (int i = 0; i < 32; ++i) {
    float x = v[i];
    float a = fminf(fabsf(x) * rscale, 6.0f);
    float rstep = a >= 4.0f ? 0.5f : (a >= 2.0f ? 1.0f : 2.0f);
    float step  = a >= 4.0f ? 2.0f : (a >= 2.0f ? 1.0f : 0.5f);
    float q = rintf(a * rstep) * step;          // RNE onto e2m1 grid
    uint32_t uq = __float_as_uint(q);
    int Eq = (int)(uq >> 23) - 127;
    uint32_t code = (q == 0.0f) ? 0u
                  : (Eq < 0 ? 1u
                            : (((uint32_t)(Eq + 1) << 1) | ((uq >> 22) & 1u)));
    code |= (__float_as_uint(x) >> 31) << 3;
    dw[i >> 3] |= code << (4 * (i & 7));
  }
  uint4 o; o.x = dw[0]; o.y = dw[1]; o.z = dw[2]; o.w = dw[3];
  *(uint4*)(packed + (size_t)g * 4) = o;

  int kt = kb >> 3, hik = kb & 1, ks = (kb >> 1) & 3;
  scales[(size_t)((kt * 2 + hik) * R + row) * 4 + ks] = (uint8_t)(E - 2 + 127);
}

// ---------------------------------------------------------------------------
// MXFP4 GEMM, B^T, 256x256 tile, BK=256, 8 waves (2Mx4N), 4-phase/K-tile
// counted-vmcnt schedule (10 VMEM/wave/tile, VMW(8) per boundary, no drain).
// LDS 136KB: 2 x {A 32K | B 32K} + 2 x {Asc 2K | Bsc 2K}. Zero register
// global loads in the loop (scales staged to LDS too) => exact ledger.
// ---------------------------------------------------------------------------
#define MFMA4(a, b, c, sa, sb) \
  __builtin_amdgcn_mfma_scale_f32_32x32x64_f8f6f4((a), (b), (c), 4, 4, 0, (sa), 0, (sb))
#define BARRIER { asm volatile("" ::: "memory"); __builtin_amdgcn_s_barrier(); asm volatile("" ::: "memory"); }
#define LGKM0  asm volatile("s_waitcnt lgkmcnt(0)" ::: "memory")
#define VMW(n) asm volatile("s_waitcnt vmcnt(" #n ")" ::: "memory")

__device__ __forceinline__ v8i frag4(const uint8_t* p) {
  v4i lo = *(const v4i*)p;
  v8i r;
  r[0] = lo[0]; r[1] = lo[1]; r[2] = lo[2]; r[3] = lo[3];
  r[4] = 0; r[5] = 0; r[6] = 0; r[7] = 0;
  return r;
}

__global__ __launch_bounds__(512, 2) void gemm_fp4_8ph(
    const uint8_t* __restrict__ Apk, const uint8_t* __restrict__ Bpk,
    const uint32_t* __restrict__ Asc, const uint32_t* __restrict__ Bsc,
    const float* __restrict__ bias, float* __restrict__ C) {
  const int N = 16384;
  __shared__ uint8_t lds[139264];

  const int tid = threadIdx.x, lane = tid & 63, wv = tid >> 6;
  const int wm = wv >> 2, wn = wv & 3;           // 2M x 4N waves
  const int hi = lane >> 5, r32 = lane & 31;

  // XCD-aware bijective swizzle (2048 blocks, 8m x 4n clusters per XCD)
  const int bid = blockIdx.x;
  const int xcd = bid & 7, idx = bid >> 3, st = idx >> 5;
  const int mT = ((st & 3) * 8 + (idx & 7)) * 256;
  const int nT = (xcd * 8 + (st >> 2) * 4 + ((idx >> 3) & 3)) * 256;

  // ---- operand staging map: per phase 16 instrs (A8+B8); wave wv issues 2.
  const int sOp = wv >> 2;                 // 0:A 1:B
  const int sR2 = (wv >> 1) & 1;           // kc LSB
  const int s0  = 2 * (wv & 1);            // row-block base (e adds 0/1)
  const uint8_t* opBase = sOp ? Bpk : Apk;
  const size_t RB = sOp ? (size_t)16384 * 16 : (size_t)8192 * 16;  // bytes/kb
  const int T0 = sOp ? nT : mT;
  const size_t gOff0 = (size_t)(T0 + (s0 + 0) * 64 + lane) * 16;
  const size_t gOff1 = (size_t)(T0 + (s0 + 1) * 64 + lane) * 16;
  const int dOff0 = sOp * 32768 + sR2 * 4096 + (s0 + 0) * 1024 + lane * 16;
  const int dOff1 = sOp * 32768 + sR2 * 4096 + (s0 + 1) * 1024 + lane * 16;

  auto STG_OPS = [&](int kt, int a, int bb) {
    const uint8_t* g0 = opBase + (size_t)(kt * 8 + a + sR2) * RB;
    uint8_t* l = &lds[bb * 65536 + a * 4096];
    gload_lds16(g0 + gOff0, l + dOff0);
    gload_lds16(g0 + gOff1, l + dOff1);
  };

  // ---- scale staging: 16 width-4 instrs; wave wv: op=sOp, hi=sR2, q=s0+e
  const uint32_t* scBase = sOp ? Bsc : Asc;
  const int Rrows = sOp ? 16384 : 8192;
  auto STG_SC = [&](int kt, int bb) {
    const uint32_t* g = scBase + (size_t)(kt * 2 + sR2) * Rrows + T0;
    uint8_t* l = &lds[131072 + bb * 4096 + sOp * 2048 + sR2 * 1024];
    gload_lds4(g + (s0 + 0) * 64 + lane, l + (s0 + 0) * 256 + lane * 4);
    gload_lds4(g + (s0 + 1) * 64 + lane, l + (s0 + 1) * 256 + lane * 4);
  };

  // ---- compute-side addressing
  const int aRd = hi * 4096 + (wm * 128 + r32) * 16;            // +j*8192 +mf*512
  const int bRd = 32768 + hi * 4096 + (wn * 64 + r32) * 16;     // +j*8192 +nf*512
  const int aSc = 131072 + hi * 1024 + (wm * 128 + r32) * 4;    // +bb*4096 +mf*128
  const int bSc = 131072 + 2048 + hi * 1024 + (wn * 64 + r32) * 4;

  v16f acc[4][2] = {};
  uint32_t saD[4], sbD[2];

#define FRAGS(bb, j) \
    v8i fA[4], fB[2]; \
    _Pragma("unroll") for (int mf = 0; mf < 4; ++mf) \
      fA[mf] = frag4(&lds[(bb) * 65536 + (j) * 8192 + aRd + mf * 512]); \
    _Pragma("unroll") for (int nf = 0; nf < 2; ++nf) \
      fB[nf] = frag4(&lds[(bb) * 65536 + (j) * 8192 + bRd + nf * 512]);

#define SCRD(bb) \
    _Pragma("unroll") for (int mf = 0; mf < 4; ++mf) \
      saD[mf] = *(const uint32_t*)&lds[(bb) * 4096 + aSc + mf * 128]; \
    _Pragma("unroll") for (int nf = 0; nf < 2; ++nf) \
      sbD[nf] = *(const uint32_t*)&lds[(bb) * 4096 + bSc + nf * 128];

#define MM8(j) \
    __builtin_amdgcn_s_setprio(1); \
    _Pragma("unroll") for (int mf = 0; mf < 4; ++mf) \
    _Pragma("unroll") for (int nf = 0; nf < 2; ++nf) \
      acc[mf][nf] = MFMA4(fA[mf], fB[nf], acc[mf][nf], \
                          (int)((saD[mf] >> (8 * (j))) & 255u), \
                          (int)((sbD[nf] >> (8 * (j))) & 255u)); \
    __builtin_amdgcn_s_setprio(0);

#define PH(bb, j, ISSUE, WAITBAR) { \
    FRAGS(bb, j); \
    if ((j) == 0) { SCRD(bb); } \
    ISSUE; \
    BARRIER; LGKM0; \
    MM8(j); \
    WAITBAR; }

  // ---- prologue: tile0 full (10 ops), tile1 minus kc6,7 (8 ops)
  STG_OPS(0, 0, 0); STG_OPS(0, 2, 0); STG_OPS(0, 4, 0); STG_OPS(0, 6, 0);
  STG_SC(0, 0);
  STG_OPS(1, 0, 1); STG_OPS(1, 2, 1); STG_OPS(1, 4, 1);
  STG_SC(1, 1);
  VMW(8);   // tile0 resident; tile1's 8 ops in flight
  BARRIER;

  // ---- main: 16 K-tiles; tiles 2i (buf0), 2i+1 (buf1); prefetch dist 2
#pragma unroll 1
  for (int i = 0; i < 7; ++i) {
    const int t0 = 2 * i;
    PH(0, 0, { STG_OPS(t0 + 1, 6, 1); },                       BARRIER);
    PH(0, 1, { STG_OPS(t0 + 2, 0, 0); STG_SC(t0 + 2, 0); },    BARRIER);
    PH(0, 2, { STG_OPS(t0 + 2, 2, 0); },                       BARRIER);
    PH(0, 3, { STG_OPS(t0 + 2, 4, 0); },                       { VMW(8); BARRIER; });
    PH(1, 0, { STG_OPS(t0 + 2, 6, 0); },                       BARRIER);
    PH(1, 1, { STG_OPS(t0 + 3, 0, 1); STG_SC(t0 + 3, 1); },    BARRIER);
    PH(1, 2, { STG_OPS(t0 + 3, 2, 1); },                       BARRIER);
    PH(1, 3, { STG_OPS(t0 + 3, 4, 1); },                       { VMW(8); BARRIER; });
  }
  // ---- peeled tail: tiles 14 (buf0), 15 (buf1)
  PH(0, 0, { STG_OPS(15, 6, 1); }, BARRIER);
  PH(0, 1, {;},                    BARRIER);
  PH(0, 2, {;},                    BARRIER);
  PH(0, 3, {;},                    { VMW(0); BARRIER; });
  PH(1, 0, {;},                    BARRIER);
  PH(1, 1, {;},                    BARRIER);
  PH(1, 2, {;},                    BARRIER);
  PH(1, 3, {;},                    {;});

  // ---- epilogue: 32x32 C/D layout col=lane&31, row=(q&3)+8*(q>>2)+4*hi
#pragma unroll
  for (int nf = 0; nf < 2; ++nf) {
    const int col = nT + wn * 64 + nf * 32 + r32;
    const float bv = bias[col];
#pragma unroll
    for (int mf = 0; mf < 4; ++mf) {
      const int rbase = mT + wm * 128 + mf * 32 + 4 * hi;
#pragma unroll
      for (int q = 0; q < 16; ++q) {
        const int rowl = (q & 3) + 8 * (q >> 2);
        C[(size_t)(rbase + rowl) * N + col] = acc[mf][nf][q] + bv;
      }
    }
  }
}

// ---------------------------------------------------------------------------
extern "C" void kernel_launch(void* const* d_in, const int* in_sizes, int n_in,
                              void* d_out, int out_size, void* d_ws, size_t ws_size,
                              hipStream_t stream) {
  const float* x    = (const float*)d_in[0];   // 8192 x 4096
  const float* w    = (const float*)d_in[1];   // 16384 x 4096
  const float* bias = (const float*)d_in[2];   // 16384
  float* out = (float*)d_out;                  // 8192 x 16384 fp32

  uint8_t* x_pk = (uint8_t*)d_ws;                        // 16 MB
  uint8_t* w_pk = x_pk + (size_t)16 * 1024 * 1024;       // 32 MB
  uint8_t* x_sc = w_pk + (size_t)32 * 1024 * 1024;       // 1 MB
  uint8_t* w_sc = x_sc + (size_t)1  * 1024 * 1024;       // 2 MB

  quant_fp4_kernel<<<4096, 256, 0, stream>>>(x, (uint32_t*)x_pk, x_sc, 8192, 13);
  quant_fp4_kernel<<<8192, 256, 0, stream>>>(w, (uint32_t*)w_pk, w_sc, 16384, 14);

  gemm_fp4_8ph<<<2048, dim3(512), 0, stream>>>(
      x_pk, w_pk, (const uint32_t*)x_sc, (const uint32_t*)w_sc, bias, out);
}